// Round 17
// baseline (457.785 us; speedup 1.0000x reference)
//
#include <hip/hip_runtime.h>

// y[b, n*DOUT+o] = sum_i x[b,n,i] * W[n,i,o] + bias[n,o]
// B=2048, N=64, DIN=512, DOUT=512, fp32 in/out, bf16 MFMA (fp32 accum).
// R13: ZERO-LDS, ZERO-BARRIER streaming GEMM. Each wave owns an independent
// 64x64 output tile; A and B MFMA fragments are read directly from global
// (W bf16 = 33.5MB is L2/XCD-resident via node->XCD affinity; x is
// L3-resident). fp32->bf16 cvt in-register (VALU was idle). No staging, no
// sync: the compiler pipelines the fully-unrolled K-chain without fences.

#define NN 64
#define DIN 512
#define DOUT 512
#define ROWSTRIDE (NN * DIN)
#define OUTSTRIDE (NN * DOUT)

typedef __bf16 bf16x8 __attribute__((ext_vector_type(8)));
typedef float f32x4 __attribute__((ext_vector_type(4)));

__device__ __forceinline__ unsigned short f2bf(float f) {
    return __builtin_bit_cast(unsigned short, (__bf16)f);  // RNE
}
__device__ __forceinline__ unsigned int f2bf2(float a, float b) {
    return (unsigned int)f2bf(a) | ((unsigned int)f2bf(b) << 16);
}

// ---- pre-pass: Wt[n][o][i] = bf16(W[n][i][o]) ----
__global__ void wt_transpose_kernel(const float* __restrict__ W,
                                    unsigned short* __restrict__ Wt) {
    __shared__ float tile[32][33];
    const int n  = blockIdx.z;
    const int i0 = blockIdx.x * 32;
    const int o0 = blockIdx.y * 32;
    const float* Wn = W + (size_t)n * DIN * DOUT;
    unsigned short* Wtn = Wt + (size_t)n * DIN * DOUT;
    const int tx = threadIdx.x, ty = threadIdx.y;
#pragma unroll
    for (int q = 0; q < 4; ++q)
        tile[ty + q * 8][tx] = Wn[(size_t)(i0 + ty + q * 8) * DOUT + (o0 + tx)];
    __syncthreads();
#pragma unroll
    for (int q = 0; q < 4; ++q)
        Wtn[(size_t)(o0 + ty + q * 8) * DIN + (i0 + tx)] = f2bf(tile[tx][ty + q * 8]);
}

// ---- main GEMM: zero LDS, zero barriers ----
__global__ __launch_bounds__(256, 3) void node_gemm_kernel(
    const float* __restrict__ X, const unsigned short* __restrict__ Wt,
    const float* __restrict__ Bias, float* __restrict__ Out) {
    // grid 4096 = 64 nodes x 16 mtiles x 4 ntiles; node -> XCD affinity,
    // ntile-minor so blocks sharing x rows are XCD-co-resident (L2 hits).
    const int bid  = blockIdx.x;
    const int xcd  = bid & 7;
    const int seq  = bid >> 3;              // 0..511
    const int node = (seq >> 6) * 8 + xcd;  // 0..63
    const int rem  = seq & 63;
    const int mtile = rem >> 2;
    const int ntile = rem & 3;
    const int brow = mtile * 128;
    const int bcol = ntile * 128;

    const int tid  = threadIdx.x;
    const int lane = tid & 63;
    const int w    = tid >> 6;              // 0..3
    const int wm   = w >> 1;                // 0..1
    const int wn   = w & 1;                 // 0..1

    const int frow = lane & 15;
    const int akk  = lane >> 4;             // 0..3

    // per-fragment global base pointers (K-contiguous in both operands)
    const int row0 = brow + wm * 64 + frow;
    const int col0 = bcol + wn * 64 + frow;
    const float* xr0 = X + (size_t)row0 * ROWSTRIDE + node * DIN + akk * 8;
    const unsigned short* wc0 =
        Wt + (size_t)node * DIN * DOUT + (size_t)col0 * DIN + akk * 8;

    f32x4 acc[4][4] = {};

#pragma unroll
    for (int kt = 0; kt < 16; ++kt) {
        const int ko = kt * 32;  // K elements per step
        bf16x8 bq[4];
#pragma unroll
        for (int n = 0; n < 4; ++n)
            bq[n] = *reinterpret_cast<const bf16x8*>(wc0 + (size_t)n * 16 * DIN + ko);
        bf16x8 af[4];
#pragma unroll
        for (int m = 0; m < 4; ++m) {
            const float* p = xr0 + (size_t)m * 16 * ROWSTRIDE + ko;
            const float4 lo = *reinterpret_cast<const float4*>(p);
            const float4 hi = *reinterpret_cast<const float4*>(p + 4);
            uint4 pk;
            pk.x = f2bf2(lo.x, lo.y);
            pk.y = f2bf2(lo.z, lo.w);
            pk.z = f2bf2(hi.x, hi.y);
            pk.w = f2bf2(hi.z, hi.w);
            af[m] = __builtin_bit_cast(bf16x8, pk);
        }
#pragma unroll
        for (int m = 0; m < 4; ++m)
#pragma unroll
            for (int n = 0; n < 4; ++n)
                acc[m][n] = __builtin_amdgcn_mfma_f32_16x16x32_bf16(af[m], bq[n], acc[m][n], 0, 0, 0);
    }

    // epilogue: D mapping col = lane&15, row = (lane>>4)*4 + j
    const float* bn = Bias + node * DOUT + bcol;
    float* outb = Out + (size_t)brow * OUTSTRIDE + node * DOUT + bcol;
#pragma unroll
    for (int n = 0; n < 4; ++n) {
        const int col = wn * 64 + n * 16 + frow;
        const float bias = bn[col];
#pragma unroll
        for (int m = 0; m < 4; ++m) {
            const int r0 = wm * 64 + m * 16 + akk * 4;
#pragma unroll
            for (int j = 0; j < 4; ++j)
                outb[(size_t)(r0 + j) * OUTSTRIDE + col] = acc[m][n][j] + bias;
        }
    }
}

extern "C" void kernel_launch(void* const* d_in, const int* in_sizes, int n_in,
                              void* d_out, int out_size, void* d_ws, size_t ws_size,
                              hipStream_t stream) {
    const float* x = (const float*)d_in[0];      // [2048, 64, 512]
    const float* W = (const float*)d_in[1];      // [64, 512, 512]
    const float* b = (const float*)d_in[2];      // [64, 512]
    float* out = (float*)d_out;                  // [2048, 64*512]
    unsigned short* Wt = (unsigned short*)d_ws;  // bf16 [64][512][512] = 33.5 MB

    wt_transpose_kernel<<<dim3(DIN / 32, DOUT / 32, NN), dim3(32, 8), 0, stream>>>(W, Wt);
    node_gemm_kernel<<<dim3(4096), dim3(256), 0, stream>>>(x, Wt, b, out);
}